// Round 13
// baseline (226.268 us; speedup 1.0000x reference)
//
#include <hip/hip_runtime.h>
#include <hip/hip_bf16.h>
#include <stdint.h>

// BertSelfAttention: B=4, S=2048, D=1024, H=16, HD=64
// Pipeline: [cvt: X,W -> bf16 once] ->
//   per head-chunk: [qkv_gemm: bf16 MFMA, global_load_lds staging, fused RoPE,
//                    Q/K -> [bh,s,hd], V -> V^T [bh,hd,s] directly]
//                   [attn: flash attn, unshifted-exp2 softmax (scale cancels),
//                    serial K/V staging, 2 barriers/tile, lsum via ones-MFMA]
// MEASURED ledger (this session):
//   setprio: ~0 (R7 144.5 vs R10 144.0).  reg-held prefetch: -9% (R8, VGPR
//   60->76, occ 34->26).  LDS dbuf + gload_lds: -13% (R11, LDS 37.9->52.2KB,
//   occ 34->24.5 -- occupancy is the latency cover; don't spend it).
//   R12: occupancy-neutral VALU/barrier cuts only.

typedef __attribute__((ext_vector_type(4))) float    f32x4;
typedef __attribute__((ext_vector_type(8))) __bf16   bf16x8;
typedef __attribute__((ext_vector_type(8))) unsigned short ushort8;
typedef __attribute__((ext_vector_type(4))) unsigned short ushort4v;

// 0.125 (1/sqrt(64)) * log2(e): scores come out in exp2-domain
#define QSCALE 0.18033688011112042f

#define GL16(g, l)                                                            \
  __builtin_amdgcn_global_load_lds(                                           \
      (const __attribute__((address_space(1))) void*)(g),                     \
      (__attribute__((address_space(3))) void*)(l), 16, 0, 0)

__device__ inline unsigned short bf(float f) {
  return __builtin_bit_cast(unsigned short, (__bf16)f);
}

// ---------------- f32 -> bf16 convert pre-pass ----------------
__global__ __launch_bounds__(256) void cvt_bf16(
    const float* __restrict__ X,
    const float* __restrict__ Wq, const float* __restrict__ Wk,
    const float* __restrict__ Wv,
    unsigned short* __restrict__ Xb, unsigned short* __restrict__ Wb)
{
  const int seg = blockIdx.y;
  const float* __restrict__ src = (seg == 0) ? X : (seg == 1) ? Wq : (seg == 2) ? Wk : Wv;
  unsigned short* __restrict__ dst = (seg == 0) ? Xb : Wb + (size_t)(seg - 1) * 1048576;
  const size_t n8 = (seg == 0) ? (size_t)1048576 : (size_t)131072;  // chunks of 8
  const size_t stride = (size_t)gridDim.x * 256;
  for (size_t i = blockIdx.x * 256 + threadIdx.x; i < n8; i += stride) {
    const float4 a = *reinterpret_cast<const float4*>(src + i * 8);
    const float4 b = *reinterpret_cast<const float4*>(src + i * 8 + 4);
    ushort8 o = { bf(a.x), bf(a.y), bf(a.z), bf(a.w), bf(b.x), bf(b.y), bf(b.z), bf(b.w) };
    *reinterpret_cast<ushort8*>(dst + i * 8) = o;
  }
}

// ---------------- QKV GEMM (bf16, global_load_lds) + fused RoPE ----------------
__global__ __launch_bounds__(256) void qkv_gemm(
    const unsigned short* __restrict__ Xb, const unsigned short* __restrict__ Wb,
    const float* __restrict__ rc, const float* __restrict__ rs,
    unsigned short* __restrict__ Qb, unsigned short* __restrict__ Kb,
    unsigned short* __restrict__ VbT, int col0, int nheads_c, int gx)
{
  const int nwg = gridDim.x;
  const int q8 = nwg >> 3;
  int w = (blockIdx.x % 8) * q8 + blockIdx.x / 8;
  const int z = w / (gx * 64);
  const int r = w - z * gx * 64;
  const int brow = (r / gx) * 128;
  const int bcol = (r % gx) * 128;

  const unsigned short* __restrict__ Wz = Wb + (size_t)z * 1048576;

  const int tid  = threadIdx.x;
  const int lane = tid & 63;
  const int wid  = tid >> 6;
  const int wm = wid >> 1, wn = wid & 1;     // 2x2 waves, each 64x64
  const int col16 = lane & 15, rowg = lane >> 4;

  __shared__ unsigned short As[128 * 32];    // linear (global_load_lds dest)
  __shared__ unsigned short Bs[128 * 32];

  f32x4 acc[4][4];
  #pragma unroll
  for (int m = 0; m < 4; ++m)
    #pragma unroll
    for (int n = 0; n < 4; ++n) acc[m][n] = (f32x4)0.f;

  const int srow = wid * 16 + (lane >> 2);
  const int scol = (lane & 3) * 8;
  const unsigned short* gA0 = Xb + (size_t)(brow + srow) * 1024 + scol;
  const unsigned short* gA1 = gA0 + (size_t)64 * 1024;
  const unsigned short* gB0 = Wz + (size_t)(col0 + bcol + srow) * 1024 + scol;
  const unsigned short* gB1 = gB0 + (size_t)64 * 1024;
  unsigned short* lA0 = &As[wid * 16 * 32];
  unsigned short* lA1 = &As[(64 + wid * 16) * 32];
  unsigned short* lB0 = &Bs[wid * 16 * 32];
  unsigned short* lB1 = &Bs[(64 + wid * 16) * 32];

  for (int k0 = 0; k0 < 1024; k0 += 32) {
    GL16(gA0 + k0, lA0);
    GL16(gA1 + k0, lA1);
    GL16(gB0 + k0, lB0);
    GL16(gB1 + k0, lB1);
    __syncthreads();

    bf16x8 af[4], bfv[4];
    #pragma unroll
    for (int m = 0; m < 4; ++m)
      af[m] = __builtin_bit_cast(bf16x8, *reinterpret_cast<const ushort8*>(
                &As[(wm * 64 + m * 16 + col16) * 32 + rowg * 8]));
    #pragma unroll
    for (int n = 0; n < 4; ++n)
      bfv[n] = __builtin_bit_cast(bf16x8, *reinterpret_cast<const ushort8*>(
                &Bs[(wn * 64 + n * 16 + col16) * 32 + rowg * 8]));
    #pragma unroll
    for (int m = 0; m < 4; ++m)
      #pragma unroll
      for (int n = 0; n < 4; ++n)
        acc[m][n] = __builtin_amdgcn_mfma_f32_16x16x32_bf16(af[m], bfv[n], acc[m][n], 0, 0, 0);
    __syncthreads();
  }

  #pragma unroll
  for (int m = 0; m < 4; ++m) {
    #pragma unroll
    for (int n = 0; n < 4; ++n) {
      const int e  = bcol + wn * 64 + n * 16 + col16;   // chunk-local feature
      const int hl = e >> 6, hd = e & 63;               // chunk-local head
      if (z == 2) {
        const int row0 = brow + wm * 64 + m * 16 + rowg * 4;
        const int b = row0 >> 11, s0 = row0 & 2047;
        ushort4v o = { bf(acc[m][n][0]), bf(acc[m][n][1]), bf(acc[m][n][2]), bf(acc[m][n][3]) };
        *reinterpret_cast<ushort4v*>(
            VbT + ((size_t)(b * nheads_c + hl) * 64 + hd) * 2048 + s0) = o;
      } else {
        unsigned short* __restrict__ outp = (z == 0) ? Qb : Kb;
        #pragma unroll
        for (int j = 0; j < 4; ++j) {
          const int row = brow + wm * 64 + m * 16 + rowg * 4 + j;
          const int b = row >> 11, s = row & 2047;
          const float rot = (n < 2) ? -acc[m][n + 2][j] : acc[m][n - 2][j];
          float v = acc[m][n][j] * rc[s * 64 + hd] + rot * rs[s * 64 + hd];
          if (z == 0) v *= QSCALE;
          outp[((size_t)(b * nheads_c + hl) * 2048 + s) * 64 + hd] = bf(v);
        }
      }
    }
  }
}

// ---------------- Flash attention ----------------
// Per tile: [stage K/V -> sync -> QKT -> exp2 -> P write (wave-private rows,
// NO barrier) -> PV + ones-lsum MFMA -> sync].  p = exp2(s) un-shifted: the
// scale factor cancels between acc and accL at normalization.
__global__ __launch_bounds__(256) void attn(
    const unsigned short* __restrict__ Qb, const unsigned short* __restrict__ Kb,
    const unsigned short* __restrict__ VbT, float* __restrict__ out,
    int col0, int nheads_c)
{
  const int tid = threadIdx.x, lane = tid & 63, wq = tid >> 6;
  const int col16 = lane & 15, rowg = lane >> 4;

  // XCD-aware bijective swizzle (nwg is a multiple of 128)
  int wg = blockIdx.x;
  const int qx = (int)gridDim.x >> 3;
  wg = (wg & 7) * qx + (wg >> 3);
  const int bh = wg >> 4;
  const int q0 = (wg & 15) * 128;
  const int b = bh / nheads_c, hl = bh - b * nheads_c;
  const int hg = (col0 >> 6) + hl;
  const size_t base = (size_t)bh * 2048 * 64;

  __shared__ unsigned short Ks[64 * 72];   // [key][hd], +8 pad
  __shared__ unsigned short Vt[64 * 72];   // [hd][key], +8 pad
  __shared__ unsigned short Ps[128 * 68];  // [q][key], +4 pad; doubles as Q staging
  __shared__ unsigned short Ones[16 * 64]; // col-0 ones B-fragment for lsum MFMA

  const int r  = tid >> 3, c  = (tid & 7) * 8;
  const int vr = tid >> 2, vc = (tid & 3) * 16;

  // one-shot Ones init (row 0 = 1.0 bf16, rows 1-15 = 0)
  {
    const int row = tid >> 4, c4 = (tid & 15) * 4;
    const unsigned short v = (row == 0) ? (unsigned short)0x3F80 : (unsigned short)0;
    ushort4v o = { v, v, v, v };
    *reinterpret_cast<ushort4v*>(&Ones[row * 64 + c4]) = o;
  }

  // stage Q tile -> Ps
  #pragma unroll
  for (int p = 0; p < 4; ++p) {
    const int row = p * 32 + r;
    ushort8 v = *reinterpret_cast<const ushort8*>(Qb + base + (size_t)(q0 + row) * 64 + c);
    *reinterpret_cast<ushort8*>(&Ps[row * 68 + c]) = v;
  }
  __syncthreads();
  bf16x8 qf[2][2];
  #pragma unroll
  for (int m = 0; m < 2; ++m)
    #pragma unroll
    for (int ks = 0; ks < 2; ++ks)
      qf[m][ks] = __builtin_bit_cast(bf16x8, *reinterpret_cast<const ushort8*>(
          &Ps[(wq * 32 + m * 16 + col16) * 68 + ks * 32 + rowg * 8]));

  f32x4 acc[2][4], accL[2];
  #pragma unroll
  for (int m = 0; m < 2; ++m) {
    accL[m] = (f32x4)0.f;
    #pragma unroll
    for (int hf = 0; hf < 4; ++hf) acc[m][hf] = (f32x4)0.f;
  }

  for (int kt = 0; kt < 32; ++kt) {
    const int key0 = kt * 64;
    // stage K (row-major) and V^T (transposed in global already)
    {
      ushort8 k0 = *reinterpret_cast<const ushort8*>(Kb + base + (size_t)(key0 + r) * 64 + c);
      ushort8 k1 = *reinterpret_cast<const ushort8*>(Kb + base + (size_t)(key0 + 32 + r) * 64 + c);
      ushort8 v0 = *reinterpret_cast<const ushort8*>(VbT + base + (size_t)vr * 2048 + key0 + vc);
      ushort8 v1 = *reinterpret_cast<const ushort8*>(VbT + base + (size_t)vr * 2048 + key0 + vc + 8);
      *reinterpret_cast<ushort8*>(&Ks[r * 72 + c]) = k0;
      *reinterpret_cast<ushort8*>(&Ks[(32 + r) * 72 + c]) = k1;
      *reinterpret_cast<ushort8*>(&Vt[vr * 72 + vc]) = v0;
      *reinterpret_cast<ushort8*>(&Vt[vr * 72 + vc + 8]) = v1;
    }
    __syncthreads();

    // S*log2e = Q @ K^T (Q pre-scaled) -> col=key(lane&15), row=q
    f32x4 sc[2][4];
    #pragma unroll
    for (int m = 0; m < 2; ++m)
      #pragma unroll
      for (int kf = 0; kf < 4; ++kf) sc[m][kf] = (f32x4)0.f;
    #pragma unroll
    for (int kf = 0; kf < 4; ++kf) {
      #pragma unroll
      for (int ks = 0; ks < 2; ++ks) {
        bf16x8 kfrag = __builtin_bit_cast(bf16x8, *reinterpret_cast<const ushort8*>(
            &Ks[(kf * 16 + col16) * 72 + ks * 32 + rowg * 8]));
        sc[0][kf] = __builtin_amdgcn_mfma_f32_16x16x32_bf16(qf[0][ks], kfrag, sc[0][kf], 0, 0, 0);
        sc[1][kf] = __builtin_amdgcn_mfma_f32_16x16x32_bf16(qf[1][ks], kfrag, sc[1][kf], 0, 0, 0);
      }
    }

    // softmax numerator: p = exp2(s), un-shifted (scale cancels in normalize).
    // P -> LDS bf16; rows are wave-private for write AND read -> no barrier.
    #pragma unroll
    for (int m = 0; m < 2; ++m)
      #pragma unroll
      for (int kf = 0; kf < 4; ++kf)
        #pragma unroll
        for (int j = 0; j < 4; ++j)
          Ps[(wq * 32 + m * 16 + rowg * 4 + j) * 68 + kf * 16 + col16] =
              bf(__builtin_exp2f(sc[m][kf][j]));

    // O += P @ V ; lsum via ones-column fragment (extra MFMA, zero VALU)
    #pragma unroll
    for (int ks = 0; ks < 2; ++ks) {
      bf16x8 pf[2];
      #pragma unroll
      for (int m = 0; m < 2; ++m)
        pf[m] = __builtin_bit_cast(bf16x8, *reinterpret_cast<const ushort8*>(
            &Ps[(wq * 32 + m * 16 + col16) * 68 + ks * 32 + rowg * 8]));
      #pragma unroll
      for (int hf = 0; hf < 4; ++hf) {
        bf16x8 vf = __builtin_bit_cast(bf16x8, *reinterpret_cast<const ushort8*>(
            &Vt[(hf * 16 + col16) * 72 + ks * 32 + rowg * 8]));
        acc[0][hf] = __builtin_amdgcn_mfma_f32_16x16x32_bf16(pf[0], vf, acc[0][hf], 0, 0, 0);
        acc[1][hf] = __builtin_amdgcn_mfma_f32_16x16x32_bf16(pf[1], vf, acc[1][hf], 0, 0, 0);
      }
      bf16x8 of = __builtin_bit_cast(bf16x8, *reinterpret_cast<const ushort8*>(
          &Ones[col16 * 64 + ks * 32 + rowg * 8]));
      accL[0] = __builtin_amdgcn_mfma_f32_16x16x32_bf16(pf[0], of, accL[0], 0, 0, 0);
      accL[1] = __builtin_amdgcn_mfma_f32_16x16x32_bf16(pf[1], of, accL[1], 0, 0, 0);
    }
    __syncthreads();   // all waves done with Ks/Vt before next stage
  }

  // normalize + write [B,S,D] f32.  accL[m][j] holds lsum at col16==0 lanes.
  #pragma unroll
  for (int m = 0; m < 2; ++m)
    #pragma unroll
    for (int j = 0; j < 4; ++j) {
      const float l = __shfl(accL[m][j], lane & 48);
      const float inv = 1.0f / l;
      const int s = q0 + wq * 32 + m * 16 + rowg * 4 + j;
      #pragma unroll
      for (int hf = 0; hf < 4; ++hf) {
        const int hd = hf * 16 + col16;
        out[((size_t)(b * 2048 + s)) * 1024 + hg * 64 + hd] = acc[m][hf][j] * inv;
      }
    }
}

extern "C" void kernel_launch(void* const* d_in, const int* in_sizes, int n_in,
                              void* d_out, int out_size, void* d_ws, size_t ws_size,
                              hipStream_t stream) {
  (void)in_sizes; (void)n_in; (void)out_size;
  const float* X  = (const float*)d_in[0];
  const float* rc = (const float*)d_in[2];
  const float* rs = (const float*)d_in[3];
  const float* Wq = (const float*)d_in[4];
  const float* Wk = (const float*)d_in[5];
  const float* Wv = (const float*)d_in[6];
  float* out = (float*)d_out;

  // ws: [Qb|Kb|VbT] (48MB/NC) + Xb (16MB) + Wb (6MB). NC = pure fn of ws_size.
  const size_t fixed = (size_t)2 * 8192 * 1024 + (size_t)3 * 2 * 1024 * 1024;
  int NC = 8;
  for (int nc = 1; nc <= 8; nc <<= 1) {
    size_t need = (size_t)3 * 2 * 8192 * (1024 / nc) + fixed;
    if (need <= ws_size) { NC = nc; break; }
  }
  const int CW = 1024 / NC;
  const int nheads_c = CW >> 6;
  const int nBH = 4 * nheads_c;
  const int gx = CW / 128;
  const size_t pc = (size_t)8192 * CW;

  unsigned short* Qb  = (unsigned short*)d_ws;
  unsigned short* Kb  = Qb + pc;
  unsigned short* VbT = Kb + pc;
  unsigned short* Xb  = VbT + pc;
  unsigned short* Wb  = Xb + (size_t)8192 * 1024;

  cvt_bf16<<<dim3(512, 4), 256, 0, stream>>>(X, Wq, Wk, Wv, Xb, Wb);

  for (int c = 0; c < NC; ++c) {
    const int col0 = c * CW;
    qkv_gemm<<<dim3(gx * 64 * 3), 256, 0, stream>>>(
        Xb, Wb, rc, rs, Qb, Kb, VbT, col0, nheads_c, gx);
    attn<<<dim3(16 * nBH), 256, 0, stream>>>(
        Qb, Kb, VbT, out, col0, nheads_c);
  }
}

// Round 14
// 220.201 us; speedup vs baseline: 1.0276x; 1.0276x over previous
//
#include <hip/hip_runtime.h>
#include <hip/hip_bf16.h>
#include <stdint.h>

// BertSelfAttention: B=4, S=2048, D=1024, H=16, HD=64
// Pipeline: [cvt: X,W -> bf16 once] ->
//   [qkv_gemm: bf16 MFMA, global_load_lds staging, fused RoPE,
//    Q/K -> [bh,s,hd], V -> V^T [bh,hd,s] directly]  (NC=1 confirmed by
//    WRITE_SIZE=32MB/dispatch)
//   [attn: flash attn, fixed-max softmax, 128-q tile, **8 waves/block**]
// MEASURED ledger (this session):
//   setprio ~0 (R7 vs R10 both 144).  reg-held prefetch -9% (R8: VGPR 60->76).
//   LDS dbuf gload_lds -13% (R11: LDS 37.9->52.2KB, occ 34->24.5).
//   unshifted-exp2 + ones-lsum-MFMA + 2-barrier -15% (R12/13: 165us,
//   conflicts 8.4e6->1.15e7, +8 MFMA/tile) -- ALL REVERTED.
//   R14: occupancy attack: 4 waves -> 8 waves/block at SAME LDS (37.9KB),
//   per-wave state halved; 4 blocks x 8 waves = 32 waves/CU theoretical.

typedef __attribute__((ext_vector_type(4))) float    f32x4;
typedef __attribute__((ext_vector_type(8))) __bf16   bf16x8;
typedef __attribute__((ext_vector_type(8))) unsigned short ushort8;
typedef __attribute__((ext_vector_type(4))) unsigned short ushort4v;

// 0.125 (1/sqrt(64)) * log2(e): scores come out in exp2-domain
#define QSCALE 0.18033688011112042f
#define SMAX   16.0f   // fixed softmax "max": exact (power-of-2 scale), scores |s|<~9

#define GL16(g, l)                                                            \
  __builtin_amdgcn_global_load_lds(                                           \
      (const __attribute__((address_space(1))) void*)(g),                     \
      (__attribute__((address_space(3))) void*)(l), 16, 0, 0)

__device__ inline unsigned short bf(float f) {
  return __builtin_bit_cast(unsigned short, (__bf16)f);
}

// ---------------- f32 -> bf16 convert pre-pass ----------------
__global__ __launch_bounds__(256) void cvt_bf16(
    const float* __restrict__ X,
    const float* __restrict__ Wq, const float* __restrict__ Wk,
    const float* __restrict__ Wv,
    unsigned short* __restrict__ Xb, unsigned short* __restrict__ Wb)
{
  const int seg = blockIdx.y;
  const float* __restrict__ src = (seg == 0) ? X : (seg == 1) ? Wq : (seg == 2) ? Wk : Wv;
  unsigned short* __restrict__ dst = (seg == 0) ? Xb : Wb + (size_t)(seg - 1) * 1048576;
  const size_t n8 = (seg == 0) ? (size_t)1048576 : (size_t)131072;  // chunks of 8
  const size_t stride = (size_t)gridDim.x * 256;
  for (size_t i = blockIdx.x * 256 + threadIdx.x; i < n8; i += stride) {
    const float4 a = *reinterpret_cast<const float4*>(src + i * 8);
    const float4 b = *reinterpret_cast<const float4*>(src + i * 8 + 4);
    ushort8 o = { bf(a.x), bf(a.y), bf(a.z), bf(a.w), bf(b.x), bf(b.y), bf(b.z), bf(b.w) };
    *reinterpret_cast<ushort8*>(dst + i * 8) = o;
  }
}

// ---------------- QKV GEMM (bf16, global_load_lds) + fused RoPE ----------------
__global__ __launch_bounds__(256) void qkv_gemm(
    const unsigned short* __restrict__ Xb, const unsigned short* __restrict__ Wb,
    const float* __restrict__ rc, const float* __restrict__ rs,
    unsigned short* __restrict__ Qb, unsigned short* __restrict__ Kb,
    unsigned short* __restrict__ VbT, int col0, int nheads_c, int gx)
{
  const int nwg = gridDim.x;
  const int q8 = nwg >> 3;
  int w = (blockIdx.x % 8) * q8 + blockIdx.x / 8;
  const int z = w / (gx * 64);
  const int r = w - z * gx * 64;
  const int brow = (r / gx) * 128;
  const int bcol = (r % gx) * 128;

  const unsigned short* __restrict__ Wz = Wb + (size_t)z * 1048576;

  const int tid  = threadIdx.x;
  const int lane = tid & 63;
  const int wid  = tid >> 6;
  const int wm = wid >> 1, wn = wid & 1;     // 2x2 waves, each 64x64
  const int col16 = lane & 15, rowg = lane >> 4;

  __shared__ unsigned short As[128 * 32];    // linear (global_load_lds dest)
  __shared__ unsigned short Bs[128 * 32];

  f32x4 acc[4][4];
  #pragma unroll
  for (int m = 0; m < 4; ++m)
    #pragma unroll
    for (int n = 0; n < 4; ++n) acc[m][n] = (f32x4)0.f;

  const int srow = wid * 16 + (lane >> 2);
  const int scol = (lane & 3) * 8;
  const unsigned short* gA0 = Xb + (size_t)(brow + srow) * 1024 + scol;
  const unsigned short* gA1 = gA0 + (size_t)64 * 1024;
  const unsigned short* gB0 = Wz + (size_t)(col0 + bcol + srow) * 1024 + scol;
  const unsigned short* gB1 = gB0 + (size_t)64 * 1024;
  unsigned short* lA0 = &As[wid * 16 * 32];
  unsigned short* lA1 = &As[(64 + wid * 16) * 32];
  unsigned short* lB0 = &Bs[wid * 16 * 32];
  unsigned short* lB1 = &Bs[(64 + wid * 16) * 32];

  for (int k0 = 0; k0 < 1024; k0 += 32) {
    GL16(gA0 + k0, lA0);
    GL16(gA1 + k0, lA1);
    GL16(gB0 + k0, lB0);
    GL16(gB1 + k0, lB1);
    __syncthreads();

    bf16x8 af[4], bfv[4];
    #pragma unroll
    for (int m = 0; m < 4; ++m)
      af[m] = __builtin_bit_cast(bf16x8, *reinterpret_cast<const ushort8*>(
                &As[(wm * 64 + m * 16 + col16) * 32 + rowg * 8]));
    #pragma unroll
    for (int n = 0; n < 4; ++n)
      bfv[n] = __builtin_bit_cast(bf16x8, *reinterpret_cast<const ushort8*>(
                &Bs[(wn * 64 + n * 16 + col16) * 32 + rowg * 8]));
    #pragma unroll
    for (int m = 0; m < 4; ++m)
      #pragma unroll
      for (int n = 0; n < 4; ++n)
        acc[m][n] = __builtin_amdgcn_mfma_f32_16x16x32_bf16(af[m], bfv[n], acc[m][n], 0, 0, 0);
    __syncthreads();
  }

  #pragma unroll
  for (int m = 0; m < 4; ++m) {
    #pragma unroll
    for (int n = 0; n < 4; ++n) {
      const int e  = bcol + wn * 64 + n * 16 + col16;   // chunk-local feature
      const int hl = e >> 6, hd = e & 63;               // chunk-local head
      if (z == 2) {
        const int row0 = brow + wm * 64 + m * 16 + rowg * 4;
        const int b = row0 >> 11, s0 = row0 & 2047;
        ushort4v o = { bf(acc[m][n][0]), bf(acc[m][n][1]), bf(acc[m][n][2]), bf(acc[m][n][3]) };
        *reinterpret_cast<ushort4v*>(
            VbT + ((size_t)(b * nheads_c + hl) * 64 + hd) * 2048 + s0) = o;
      } else {
        unsigned short* __restrict__ outp = (z == 0) ? Qb : Kb;
        #pragma unroll
        for (int j = 0; j < 4; ++j) {
          const int row = brow + wm * 64 + m * 16 + rowg * 4 + j;
          const int b = row >> 11, s = row & 2047;
          const float rot = (n < 2) ? -acc[m][n + 2][j] : acc[m][n - 2][j];
          float v = acc[m][n][j] * rc[s * 64 + hd] + rot * rs[s * 64 + hd];
          if (z == 0) v *= QSCALE;
          outp[((size_t)(b * nheads_c + hl) * 2048 + s) * 64 + hd] = bf(v);
        }
      }
    }
  }
}

// ---------------- Flash attention (8 waves, 128-q tile) ----------------
// Per tile: [stage K/V -> sync -> QKT -> softmax -> P write -> sync -> PV -> sync]
// Wave wq owns q-rows [wq*16, wq*16+16).  Same LDS as 4-wave version (37.9KB)
// -> 4 blocks/CU x 8 waves = 32 waves/CU theoretical (was 16).
__global__ __launch_bounds__(512) void attn(
    const unsigned short* __restrict__ Qb, const unsigned short* __restrict__ Kb,
    const unsigned short* __restrict__ VbT, float* __restrict__ out,
    int col0, int nheads_c)
{
  const int tid = threadIdx.x, lane = tid & 63, wq = tid >> 6;   // wq in 0..7
  const int col16 = lane & 15, rowg = lane >> 4;

  // XCD-aware bijective swizzle (nwg is a multiple of 128)
  int wg = blockIdx.x;
  const int qx = (int)gridDim.x >> 3;
  wg = (wg & 7) * qx + (wg >> 3);
  const int bh = wg >> 4;
  const int q0 = (wg & 15) * 128;
  const int b = bh / nheads_c, hl = bh - b * nheads_c;
  const int hg = (col0 >> 6) + hl;
  const size_t base = (size_t)bh * 2048 * 64;

  __shared__ unsigned short Ks[64 * 72];   // [key][hd], +8 pad
  __shared__ unsigned short Vt[64 * 72];   // [hd][key], +8 pad
  __shared__ unsigned short Ps[128 * 76];  // [q][key], +12 pad; doubles as Q staging

  const int sr = tid >> 3, sc8 = (tid & 7) * 8;   // 512 threads: 64 rows x 8x8 cols

  // stage Q tile -> Ps (2 passes of 64 rows)
  #pragma unroll
  for (int p = 0; p < 2; ++p) {
    const int row = p * 64 + sr;
    ushort8 v = *reinterpret_cast<const ushort8*>(Qb + base + (size_t)(q0 + row) * 64 + sc8);
    *reinterpret_cast<ushort8*>(&Ps[row * 76 + sc8]) = v;
  }
  __syncthreads();
  bf16x8 qf[2];
  #pragma unroll
  for (int ks = 0; ks < 2; ++ks)
    qf[ks] = __builtin_bit_cast(bf16x8, *reinterpret_cast<const ushort8*>(
        &Ps[(wq * 16 + col16) * 76 + ks * 32 + rowg * 8]));

  float lsum[4] = {0.f, 0.f, 0.f, 0.f};
  f32x4 acc[4];
  #pragma unroll
  for (int hf = 0; hf < 4; ++hf) acc[hf] = (f32x4)0.f;

  for (int kt = 0; kt < 32; ++kt) {
    const int key0 = kt * 64;
    // stage K (row-major) and V^T: one 16B load each per thread
    {
      ushort8 kv = *reinterpret_cast<const ushort8*>(Kb + base + (size_t)(key0 + sr) * 64 + sc8);
      ushort8 vv = *reinterpret_cast<const ushort8*>(VbT + base + (size_t)sr * 2048 + key0 + sc8);
      *reinterpret_cast<ushort8*>(&Ks[sr * 72 + sc8]) = kv;
      *reinterpret_cast<ushort8*>(&Vt[sr * 72 + sc8]) = vv;
    }
    __syncthreads();

    // S*log2e = Q @ K^T (Q pre-scaled) -> col=key(lane&15), row=q
    f32x4 sc[4];
    #pragma unroll
    for (int kf = 0; kf < 4; ++kf) sc[kf] = (f32x4)0.f;
    #pragma unroll
    for (int kf = 0; kf < 4; ++kf) {
      #pragma unroll
      for (int ks = 0; ks < 2; ++ks) {
        bf16x8 kfrag = __builtin_bit_cast(bf16x8, *reinterpret_cast<const ushort8*>(
            &Ks[(kf * 16 + col16) * 72 + ks * 32 + rowg * 8]));
        sc[kf] = __builtin_amdgcn_mfma_f32_16x16x32_bf16(qf[ks], kfrag, sc[kf], 0, 0, 0);
      }
    }

    // fixed-max softmax: p = exp2(s - 16) (power-of-2 scale of true numerator)
    #pragma unroll
    for (int j = 0; j < 4; ++j) {
      float ps = 0.f;
      #pragma unroll
      for (int kf = 0; kf < 4; ++kf) {
        const float p = __builtin_exp2f(sc[kf][j] - SMAX);
        sc[kf][j] = p;
        ps += p;
      }
      lsum[j] += ps;
    }

    // P -> LDS (bf16), 76-pad; wave-private rows
    #pragma unroll
    for (int kf = 0; kf < 4; ++kf)
      #pragma unroll
      for (int j = 0; j < 4; ++j)
        Ps[(wq * 16 + rowg * 4 + j) * 76 + kf * 16 + col16] = bf(sc[kf][j]);
    __syncthreads();

    // O += P @ V
    #pragma unroll
    for (int ks = 0; ks < 2; ++ks) {
      bf16x8 pf = __builtin_bit_cast(bf16x8, *reinterpret_cast<const ushort8*>(
          &Ps[(wq * 16 + col16) * 76 + ks * 32 + rowg * 8]));
      #pragma unroll
      for (int hf = 0; hf < 4; ++hf) {
        bf16x8 vf = __builtin_bit_cast(bf16x8, *reinterpret_cast<const ushort8*>(
            &Vt[(hf * 16 + col16) * 72 + ks * 32 + rowg * 8]));
        acc[hf] = __builtin_amdgcn_mfma_f32_16x16x32_bf16(pf, vf, acc[hf], 0, 0, 0);
      }
    }
    __syncthreads();
  }

  // final lsum reduce across the 16-lane group, normalize + write [B,S,D] f32
  #pragma unroll
  for (int j = 0; j < 4; ++j) {
    float l = lsum[j];
    l += __shfl_xor(l, 1);
    l += __shfl_xor(l, 2);
    l += __shfl_xor(l, 4);
    l += __shfl_xor(l, 8);
    const float inv = 1.0f / l;
    const int s = q0 + wq * 16 + rowg * 4 + j;
    #pragma unroll
    for (int hf = 0; hf < 4; ++hf) {
      const int hd = hf * 16 + col16;
      out[((size_t)(b * 2048 + s)) * 1024 + hg * 64 + hd] = acc[hf][j] * inv;
    }
  }
}

extern "C" void kernel_launch(void* const* d_in, const int* in_sizes, int n_in,
                              void* d_out, int out_size, void* d_ws, size_t ws_size,
                              hipStream_t stream) {
  (void)in_sizes; (void)n_in; (void)out_size;
  const float* X  = (const float*)d_in[0];
  const float* rc = (const float*)d_in[2];
  const float* rs = (const float*)d_in[3];
  const float* Wq = (const float*)d_in[4];
  const float* Wk = (const float*)d_in[5];
  const float* Wv = (const float*)d_in[6];
  float* out = (float*)d_out;

  // ws: [Qb|Kb|VbT] (48MB/NC) + Xb (16MB) + Wb (6MB). NC = pure fn of ws_size.
  const size_t fixed = (size_t)2 * 8192 * 1024 + (size_t)3 * 2 * 1024 * 1024;
  int NC = 8;
  for (int nc = 1; nc <= 8; nc <<= 1) {
    size_t need = (size_t)3 * 2 * 8192 * (1024 / nc) + fixed;
    if (need <= ws_size) { NC = nc; break; }
  }
  const int CW = 1024 / NC;
  const int nheads_c = CW >> 6;
  const int nBH = 4 * nheads_c;
  const int gx = CW / 128;
  const size_t pc = (size_t)8192 * CW;

  unsigned short* Qb  = (unsigned short*)d_ws;
  unsigned short* Kb  = Qb + pc;
  unsigned short* VbT = Kb + pc;
  unsigned short* Xb  = VbT + pc;
  unsigned short* Wb  = Xb + (size_t)8192 * 1024;

  cvt_bf16<<<dim3(512, 4), 256, 0, stream>>>(X, Wq, Wk, Wv, Xb, Wb);

  for (int c = 0; c < NC; ++c) {
    const int col0 = c * CW;
    qkv_gemm<<<dim3(gx * 64 * 3), 256, 0, stream>>>(
        Xb, Wb, rc, rs, Qb, Kb, VbT, col0, nheads_c, gx);
    attn<<<dim3(16 * nBH), 512, 0, stream>>>(
        Qb, Kb, VbT, out, col0, nheads_c);
  }
}

// Round 16
// 202.925 us; speedup vs baseline: 1.1150x; 1.0851x over previous
//
#include <hip/hip_runtime.h>
#include <hip/hip_bf16.h>
#include <stdint.h>

// BertSelfAttention: B=4, S=2048, D=1024, H=16, HD=64
// [cvt: X,W->bf16] -> [qkv_gemm: bf16 MFMA + RoPE; Q/K->[bh,s,hd], V->V^T]
// -> [attn: swapped-QKT 32x32 MFMA flash attn, P fully in-register
//     (cvt_pk + permlane32_swap), fixed-max softmax, 2 barriers/tile]
// R15 FAILED (absmax 0.67): permlane32_swap operand order was REVERSED
// (vdst must be the low-keys word; m214: r[0]=first-arg-updated=dw0).
// R16 = R15 with the swap via __builtin_amdgcn_permlane32_swap(w0, w2)
// (correct order, dependency-tracked). All other mappings re-verified.

typedef __attribute__((ext_vector_type(4)))  float    f32x4;
typedef __attribute__((ext_vector_type(16))) float    f32x16;
typedef __attribute__((ext_vector_type(8)))  __bf16   bf16x8;
typedef __attribute__((ext_vector_type(8)))  unsigned short ushort8;
typedef __attribute__((ext_vector_type(4)))  unsigned short ushort4v;
typedef __attribute__((ext_vector_type(4)))  uint32_t uint32x4;
typedef __attribute__((ext_vector_type(2)))  uint32_t uint32x2;

#define QSCALE 0.18033688011112042f   // 0.125 * log2(e): scores in exp2-domain
#define SMAX   16.0f                  // fixed softmax max (power-of-2 exact)

#define GL16(g, l)                                                            \
  __builtin_amdgcn_global_load_lds(                                           \
      (const __attribute__((address_space(1))) void*)(g),                     \
      (__attribute__((address_space(3))) void*)(l), 16, 0, 0)

__device__ inline unsigned short bf(float f) {
  return __builtin_bit_cast(unsigned short, (__bf16)f);
}
__device__ inline uint32_t cvtpk(float lo, float hi) {
  uint32_t r;
  asm volatile("v_cvt_pk_bf16_f32 %0, %1, %2" : "=v"(r) : "v"(lo), "v"(hi));
  return r;
}

// ---------------- f32 -> bf16 convert pre-pass ----------------
__global__ __launch_bounds__(256) void cvt_bf16(
    const float* __restrict__ X,
    const float* __restrict__ Wq, const float* __restrict__ Wk,
    const float* __restrict__ Wv,
    unsigned short* __restrict__ Xb, unsigned short* __restrict__ Wb)
{
  const int seg = blockIdx.y;
  const float* __restrict__ src = (seg == 0) ? X : (seg == 1) ? Wq : (seg == 2) ? Wk : Wv;
  unsigned short* __restrict__ dst = (seg == 0) ? Xb : Wb + (size_t)(seg - 1) * 1048576;
  const size_t n8 = (seg == 0) ? (size_t)1048576 : (size_t)131072;
  const size_t stride = (size_t)gridDim.x * 256;
  for (size_t i = blockIdx.x * 256 + threadIdx.x; i < n8; i += stride) {
    const float4 a = *reinterpret_cast<const float4*>(src + i * 8);
    const float4 b = *reinterpret_cast<const float4*>(src + i * 8 + 4);
    ushort8 o = { bf(a.x), bf(a.y), bf(a.z), bf(a.w), bf(b.x), bf(b.y), bf(b.z), bf(b.w) };
    *reinterpret_cast<ushort8*>(dst + i * 8) = o;
  }
}

// ---------------- QKV GEMM (bf16, global_load_lds) + fused RoPE ----------------
__global__ __launch_bounds__(256) void qkv_gemm(
    const unsigned short* __restrict__ Xb, const unsigned short* __restrict__ Wb,
    const float* __restrict__ rc, const float* __restrict__ rs,
    unsigned short* __restrict__ Qb, unsigned short* __restrict__ Kb,
    unsigned short* __restrict__ VbT, int col0, int nheads_c, int gx)
{
  const int nwg = gridDim.x;
  const int q8 = nwg >> 3;
  int w = (blockIdx.x % 8) * q8 + blockIdx.x / 8;
  const int z = w / (gx * 64);
  const int r = w - z * gx * 64;
  const int brow = (r / gx) * 128;
  const int bcol = (r % gx) * 128;

  const unsigned short* __restrict__ Wz = Wb + (size_t)z * 1048576;

  const int tid  = threadIdx.x;
  const int lane = tid & 63;
  const int wid  = tid >> 6;
  const int wm = wid >> 1, wn = wid & 1;     // 2x2 waves, each 64x64
  const int col16 = lane & 15, rowg = lane >> 4;

  __shared__ unsigned short As[128 * 32];
  __shared__ unsigned short Bs[128 * 32];

  f32x4 acc[4][4];
  #pragma unroll
  for (int m = 0; m < 4; ++m)
    #pragma unroll
    for (int n = 0; n < 4; ++n) acc[m][n] = (f32x4)0.f;

  const int srow = wid * 16 + (lane >> 2);
  const int scol = (lane & 3) * 8;
  const unsigned short* gA0 = Xb + (size_t)(brow + srow) * 1024 + scol;
  const unsigned short* gA1 = gA0 + (size_t)64 * 1024;
  const unsigned short* gB0 = Wz + (size_t)(col0 + bcol + srow) * 1024 + scol;
  const unsigned short* gB1 = gB0 + (size_t)64 * 1024;
  unsigned short* lA0 = &As[wid * 16 * 32];
  unsigned short* lA1 = &As[(64 + wid * 16) * 32];
  unsigned short* lB0 = &Bs[wid * 16 * 32];
  unsigned short* lB1 = &Bs[(64 + wid * 16) * 32];

  for (int k0 = 0; k0 < 1024; k0 += 32) {
    GL16(gA0 + k0, lA0);
    GL16(gA1 + k0, lA1);
    GL16(gB0 + k0, lB0);
    GL16(gB1 + k0, lB1);
    __syncthreads();

    bf16x8 af[4], bfv[4];
    #pragma unroll
    for (int m = 0; m < 4; ++m)
      af[m] = __builtin_bit_cast(bf16x8, *reinterpret_cast<const ushort8*>(
                &As[(wm * 64 + m * 16 + col16) * 32 + rowg * 8]));
    #pragma unroll
    for (int n = 0; n < 4; ++n)
      bfv[n] = __builtin_bit_cast(bf16x8, *reinterpret_cast<const ushort8*>(
                &Bs[(wn * 64 + n * 16 + col16) * 32 + rowg * 8]));
    #pragma unroll
    for (int m = 0; m < 4; ++m)
      #pragma unroll
      for (int n = 0; n < 4; ++n)
        acc[m][n] = __builtin_amdgcn_mfma_f32_16x16x32_bf16(af[m], bfv[n], acc[m][n], 0, 0, 0);
    __syncthreads();
  }

  #pragma unroll
  for (int m = 0; m < 4; ++m) {
    #pragma unroll
    for (int n = 0; n < 4; ++n) {
      const int e  = bcol + wn * 64 + n * 16 + col16;
      const int hl = e >> 6, hd = e & 63;
      if (z == 2) {
        const int row0 = brow + wm * 64 + m * 16 + rowg * 4;
        const int b = row0 >> 11, s0 = row0 & 2047;
        ushort4v o = { bf(acc[m][n][0]), bf(acc[m][n][1]), bf(acc[m][n][2]), bf(acc[m][n][3]) };
        *reinterpret_cast<ushort4v*>(
            VbT + ((size_t)(b * nheads_c + hl) * 64 + hd) * 2048 + s0) = o;
      } else {
        unsigned short* __restrict__ outp = (z == 0) ? Qb : Kb;
        #pragma unroll
        for (int j = 0; j < 4; ++j) {
          const int row = brow + wm * 64 + m * 16 + rowg * 4 + j;
          const int b = row >> 11, s = row & 2047;
          const float rot = (n < 2) ? -acc[m][n + 2][j] : acc[m][n - 2][j];
          float v = acc[m][n][j] * rc[s * 64 + hd] + rot * rs[s * 64 + hd];
          if (z == 0) v *= QSCALE;
          outp[((size_t)(b * nheads_c + hl) * 2048 + s) * 64 + hd] = bf(v);
        }
      }
    }
  }
}

// ---------------- Flash attention (swapped QK^T, in-register P) ----------------
// 4 waves x 32 q-rows = 128 q/block; grid 16 x 64bh = 1024.
// Swapped QK^T via mfma_32x32x16(K, Q): lane holds S[16 keys][q=lane&31].
// P stays in registers: cvt_pk pairs + permlane32_swap rebuild the PV
// A-fragments (frag ks needs keys ks*16 + hi*8 + j).  No P LDS.
__global__ __launch_bounds__(256) void attn(
    const unsigned short* __restrict__ Qb, const unsigned short* __restrict__ Kb,
    const unsigned short* __restrict__ VbT, float* __restrict__ out,
    int col0, int nheads_c)
{
  const int tid = threadIdx.x, lane = tid & 63, wq = tid >> 6;
  const int l31 = lane & 31, hi = lane >> 5;

  // XCD-aware bijective swizzle (nwg multiple of 128)
  int wg = blockIdx.x;
  const int qx = (int)gridDim.x >> 3;
  wg = (wg & 7) * qx + (wg >> 3);
  const int bh = wg >> 4;
  const int q0 = (wg & 15) * 128;
  const int b = bh / nheads_c, hl = bh - b * nheads_c;
  const int hg = (col0 >> 6) + hl;
  const size_t base = (size_t)bh * 2048 * 64;

  __shared__ unsigned short Ks[64 * 72];  // [key][d], stride 72 (144B, 16B-aligned)
  __shared__ unsigned short Vt[64 * 72];  // [hd][key]
  __shared__ float Ls[4 * 32];            // per-wave lsum redistribution

  // Q B-fragments direct from global (once): qf[ds] = Q[q=l31][d=ds*16+hi*8+j]
  const int qrow = q0 + wq * 32 + l31;
  bf16x8 qf[4];
  #pragma unroll
  for (int ds = 0; ds < 4; ++ds)
    qf[ds] = __builtin_bit_cast(bf16x8, *reinterpret_cast<const ushort8*>(
        Qb + base + (size_t)qrow * 64 + ds * 16 + hi * 8));

  f32x16 acc0 = (f32x16)0.f, acc1 = (f32x16)0.f;
  float ps = 0.f;

  const int sr = tid >> 3, sc8 = (tid & 7) * 8;   // staging: 32 rows x 8 chunks

  for (int kt = 0; kt < 32; ++kt) {
    const int key0 = kt * 64;
    // stage K[key][d] and V^T[hd][key] (4x16B per thread)
    {
      ushort8 k0v = *reinterpret_cast<const ushort8*>(Kb + base + (size_t)(key0 + sr) * 64 + sc8);
      ushort8 k1v = *reinterpret_cast<const ushort8*>(Kb + base + (size_t)(key0 + 32 + sr) * 64 + sc8);
      ushort8 v0v = *reinterpret_cast<const ushort8*>(VbT + base + (size_t)sr * 2048 + key0 + sc8);
      ushort8 v1v = *reinterpret_cast<const ushort8*>(VbT + base + (size_t)(32 + sr) * 2048 + key0 + sc8);
      *reinterpret_cast<ushort8*>(&Ks[sr * 72 + sc8]) = k0v;
      *reinterpret_cast<ushort8*>(&Ks[(32 + sr) * 72 + sc8]) = k1v;
      *reinterpret_cast<ushort8*>(&Vt[sr * 72 + sc8]) = v0v;
      *reinterpret_cast<ushort8*>(&Vt[(32 + sr) * 72 + sc8]) = v1v;
    }
    __syncthreads();

    // per key-block kb: S[key=kb*32+crow][q=l31] = sum_d K*Q, then exp2+pack
    bf16x8 pa[4];
    #pragma unroll
    for (int kb = 0; kb < 2; ++kb) {
      f32x16 s = (f32x16)0.f;
      #pragma unroll
      for (int ds = 0; ds < 4; ++ds) {
        bf16x8 af = __builtin_bit_cast(bf16x8, *reinterpret_cast<const ushort8*>(
            &Ks[(kb * 32 + l31) * 72 + ds * 16 + hi * 8]));
        s = __builtin_amdgcn_mfma_f32_32x32x16_bf16(af, qf[ds], s, 0, 0, 0);
      }
      float p[16];
      #pragma unroll
      for (int rg = 0; rg < 16; ++rg) {
        p[rg] = __builtin_exp2f(s[rg] - SMAX);
        ps += p[rg];
      }
      #pragma unroll
      for (int hf2 = 0; hf2 < 2; ++hf2) {     // region ks = kb*2 + hf2
        // lane (hi) holds key pairs: w0=(0,1)/(4,5), w1=(2,3)/(6,7),
        //                            w2=(8,9)/(12,13), w3=(10,11)/(14,15)
        uint32_t w0 = cvtpk(p[hf2 * 8 + 0], p[hf2 * 8 + 1]);
        uint32_t w1 = cvtpk(p[hf2 * 8 + 2], p[hf2 * 8 + 3]);
        uint32_t w2 = cvtpk(p[hf2 * 8 + 4], p[hf2 * 8 + 5]);
        uint32_t w3 = cvtpk(p[hf2 * 8 + 6], p[hf2 * 8 + 7]);
        // swap(w0 [vdst], w2 [vsrc]): r[0]=dw0 {hi0:(0,1),hi1:(8,9)},
        //                             r[1]=dw2 {hi0:(4,5),hi1:(12,13)}
        uint32x2 a02 = __builtin_amdgcn_permlane32_swap(w0, w2, false, false);
        uint32x2 a13 = __builtin_amdgcn_permlane32_swap(w1, w3, false, false);
        uint32x4 d4 = { a02[0], a13[0], a02[1], a13[1] };
        pa[kb * 2 + hf2] = __builtin_bit_cast(bf16x8, d4);
      }
    }

    // O[q][hd] += P @ V  (A = pa frags, B = V[hd=l31][key])
    #pragma unroll
    for (int ks = 0; ks < 4; ++ks) {
      bf16x8 vf0 = __builtin_bit_cast(bf16x8, *reinterpret_cast<const ushort8*>(
          &Vt[l31 * 72 + ks * 16 + hi * 8]));
      bf16x8 vf1 = __builtin_bit_cast(bf16x8, *reinterpret_cast<const ushort8*>(
          &Vt[(32 + l31) * 72 + ks * 16 + hi * 8]));
      acc0 = __builtin_amdgcn_mfma_f32_32x32x16_bf16(pa[ks], vf0, acc0, 0, 0, 0);
      acc1 = __builtin_amdgcn_mfma_f32_32x32x16_bf16(pa[ks], vf1, acc1, 0, 0, 0);
    }
    __syncthreads();
  }

  // lsum: my half + partner half; redistribute via wave-private LDS row
  ps += __shfl_xor(ps, 32);
  if (hi == 0) Ls[wq * 32 + l31] = ps;
  #pragma unroll
  for (int rg = 0; rg < 16; ++rg) {
    const int qr = (rg & 3) + 8 * (rg >> 2) + 4 * hi;
    const float inv = 1.0f / Ls[wq * 32 + qr];
    const int s = q0 + wq * 32 + qr;
    float* o = out + ((size_t)(b * 2048 + s)) * 1024 + hg * 64 + l31;
    o[0]  = acc0[rg] * inv;
    o[32] = acc1[rg] * inv;
  }
}

extern "C" void kernel_launch(void* const* d_in, const int* in_sizes, int n_in,
                              void* d_out, int out_size, void* d_ws, size_t ws_size,
                              hipStream_t stream) {
  (void)in_sizes; (void)n_in; (void)out_size;
  const float* X  = (const float*)d_in[0];
  const float* rc = (const float*)d_in[2];
  const float* rs = (const float*)d_in[3];
  const float* Wq = (const float*)d_in[4];
  const float* Wk = (const float*)d_in[5];
  const float* Wv = (const float*)d_in[6];
  float* out = (float*)d_out;

  const size_t fixed = (size_t)2 * 8192 * 1024 + (size_t)3 * 2 * 1024 * 1024;
  int NC = 8;
  for (int nc = 1; nc <= 8; nc <<= 1) {
    size_t need = (size_t)3 * 2 * 8192 * (1024 / nc) + fixed;
    if (need <= ws_size) { NC = nc; break; }
  }
  const int CW = 1024 / NC;
  const int nheads_c = CW >> 6;
  const int nBH = 4 * nheads_c;
  const int gx = CW / 128;
  const size_t pc = (size_t)8192 * CW;

  unsigned short* Qb  = (unsigned short*)d_ws;
  unsigned short* Kb  = Qb + pc;
  unsigned short* VbT = Kb + pc;
  unsigned short* Xb  = VbT + pc;
  unsigned short* Wb  = Xb + (size_t)8192 * 1024;

  cvt_bf16<<<dim3(512, 4), 256, 0, stream>>>(X, Wq, Wk, Wv, Xb, Wb);

  for (int c = 0; c < NC; ++c) {
    const int col0 = c * CW;
    qkv_gemm<<<dim3(gx * 64 * 3), 256, 0, stream>>>(
        Xb, Wb, rc, rs, Qb, Kb, VbT, col0, nheads_c, gx);
    attn<<<dim3(16 * nBH), 256, 0, stream>>>(
        Qb, Kb, VbT, out, col0, nheads_c);
  }
}